// Round 1
// baseline (229.382 us; speedup 1.0000x reference)
//
#include <hip/hip_runtime.h>

// out[i] = cos(x[i]) * cos(theta[i & 63])
// B,S,E = 8,4096,1024; HD = 64. Pure elementwise, memory-bound.
// float4 path: each thread handles 4 consecutive floats. Since the
// grid-stride (gridDim*256 float4s) is a multiple of 16 float4s = 64 floats,
// each thread's phase (i*4) & 63 is loop-invariant -> hoist cos(theta) into
// 4 registers before the loop.

__global__ __launch_bounds__(256) void qattn_kernel(
    const float* __restrict__ x,
    const float* __restrict__ theta,
    float* __restrict__ out,
    int n4)  // number of float4 elements
{
    const int tid    = blockIdx.x * blockDim.x + threadIdx.x;
    const int stride = gridDim.x * blockDim.x;  // multiple of 16 -> phase invariant

    const int base = (tid * 4) & 63;  // multiple of 4, so base..base+3 <= 63
    const float c0 = __cosf(theta[base + 0]);
    const float c1 = __cosf(theta[base + 1]);
    const float c2 = __cosf(theta[base + 2]);
    const float c3 = __cosf(theta[base + 3]);

    const float4* __restrict__ x4   = reinterpret_cast<const float4*>(x);
    float4* __restrict__       out4 = reinterpret_cast<float4*>(out);

    for (int i = tid; i < n4; i += stride) {
        float4 v = x4[i];
        float4 r;
        r.x = __cosf(v.x) * c0;
        r.y = __cosf(v.y) * c1;
        r.z = __cosf(v.z) * c2;
        r.w = __cosf(v.w) * c3;
        out4[i] = r;
    }
}

extern "C" void kernel_launch(void* const* d_in, const int* in_sizes, int n_in,
                              void* d_out, int out_size, void* d_ws, size_t ws_size,
                              hipStream_t stream) {
    const float* x     = (const float*)d_in[0];  // (B,S,E) f32
    const float* theta = (const float*)d_in[1];  // (64,) f32
    float* out         = (float*)d_out;          // (B,S,E) f32

    const int n  = out_size;       // 33,554,432
    const int n4 = n / 4;          // 8,388,608 float4s (E=1024 divisible by 4)

    const int block = 256;
    int grid = (n4 + block - 1) / block;
    if (grid > 2048) grid = 2048;  // grid-stride the rest (stride stays %16==0)

    qattn_kernel<<<grid, block, 0, stream>>>(x, theta, out, n4);
}

// Round 5
// 227.231 us; speedup vs baseline: 1.0095x; 1.0095x over previous
//
#include <hip/hip_runtime.h>

// out[i] = cos(x[i]) * cos(theta[i & 63])
// B,S,E = 8,4096,1024; HD = 64. Pure elementwise streaming, memory-bound.
// Roofline: 268 MB @ ~6.3 TB/s ~= 43 us.
//
// - Native clang ext_vector f32x4 (HIP float4 is a class -> nontemporal
//   builtin rejects it; ext_vector_type is accepted).
// - Nontemporal 16B/lane loads/stores: read-once/write-once data far larger
//   than L2 -> bypass cache write-allocate churn.
// - Grid-stride is a multiple of 64 floats, so each thread's theta phase
//   (i*4)&63 is loop-invariant: hoist 4 cos(theta) values into registers.
// - Exact trip count (16 at bench shape), unrolled x4 -> multiple loads in
//   flight per thread for HBM latency hiding.

typedef float f32x4 __attribute__((ext_vector_type(4)));

__global__ __launch_bounds__(256) void qattn_kernel(
    const float* __restrict__ x,
    const float* __restrict__ theta,
    float* __restrict__ out,
    int n4)  // number of float4 elements
{
    const int tid    = blockIdx.x * blockDim.x + threadIdx.x;
    const int stride = gridDim.x * blockDim.x;  // multiple of 16 float4s

    const int base = (tid * 4) & 63;
    const float c0 = __cosf(theta[base + 0]);
    const float c1 = __cosf(theta[base + 1]);
    const float c2 = __cosf(theta[base + 2]);
    const float c3 = __cosf(theta[base + 3]);

    const f32x4* __restrict__ x4   = reinterpret_cast<const f32x4*>(x);
    f32x4* __restrict__       out4 = reinterpret_cast<f32x4*>(out);

    const int iters = n4 / stride;  // == 16 at bench shape, exact

#pragma unroll 4
    for (int k = 0; k < iters; ++k) {
        const int i = tid + k * stride;
        f32x4 v = __builtin_nontemporal_load(&x4[i]);
        f32x4 r;
        r.x = __cosf(v.x) * c0;
        r.y = __cosf(v.y) * c1;
        r.z = __cosf(v.z) * c2;
        r.w = __cosf(v.w) * c3;
        __builtin_nontemporal_store(r, &out4[i]);
    }

    // tail (empty at the bench shape)
    const int i = tid + iters * stride;
    if (i < n4) {
        f32x4 v = x4[i];
        f32x4 r;
        r.x = __cosf(v.x) * c0;
        r.y = __cosf(v.y) * c1;
        r.z = __cosf(v.z) * c2;
        r.w = __cosf(v.w) * c3;
        out4[i] = r;
    }
}

extern "C" void kernel_launch(void* const* d_in, const int* in_sizes, int n_in,
                              void* d_out, int out_size, void* d_ws, size_t ws_size,
                              hipStream_t stream) {
    const float* x     = (const float*)d_in[0];  // (B,S,E) f32
    const float* theta = (const float*)d_in[1];  // (64,) f32
    float* out         = (float*)d_out;          // (B,S,E) f32

    const int n  = out_size;  // 33,554,432
    const int n4 = n / 4;     // 8,388,608 float4s

    const int block = 256;
    int grid = (n4 + block - 1) / block;
    if (grid > 2048) grid = 2048;  // 8192 waves; stride stays %16==0

    qattn_kernel<<<grid, block, 0, stream>>>(x, theta, out, n4);
}